// Round 11
// baseline (794.938 us; speedup 1.0000x reference)
//
#include <hip/hip_runtime.h>
#include <hip/hip_bf16.h>
#include <stdint.h>

#define NROWS 500000
#define INC 256
#define OUTC 112

typedef __attribute__((ext_vector_type(8))) short short8;
typedef __attribute__((ext_vector_type(4))) float f32x4;

static __device__ __forceinline__ uint32_t as_u32(float f) {
    union { float f; uint32_t u; } v; v.f = f; return v.u;
}
static __device__ __forceinline__ float as_f32(uint32_t u) {
    union { float f; uint32_t u; } v; v.u = u; return v.f;
}
// round-to-nearest-even bf16 (upper 16 bits); carry into exponent is correct.
static __device__ __forceinline__ unsigned short bf16_rne(float f) {
    uint32_t u = as_u32(f);
    uint32_t r = u + 0x7FFFu + ((u >> 16) & 1u);
    return (unsigned short)(r >> 16);
}
static __device__ __forceinline__ float bf16_to_f32(unsigned short h) {
    return as_f32(((uint32_t)h) << 16);
}

// convert 8 fp32 (two f32x4) -> bf16 hi + residual-lo fragments (x side keeps
// hi+lo so x-quantization error is fully compensated; W keeps hi only).
static __device__ __forceinline__ void conv8(const f32x4& a, const f32x4& b,
                                             short8& hi, short8& lo) {
    #pragma unroll
    for (int j = 0; j < 8; ++j) {
        float f = (j < 4) ? a[j] : b[j - 4];
        unsigned short h = bf16_rne(f);
        hi[j] = (short)h;
        lo[j] = (short)bf16_rne(f - bf16_to_f32(h));
    }
}

// ---------------- Prepass 1: W0*wcat0 -> bf16 hi/lo fragment layout + sorted
// relu thresholds. Fragment layout: W[(k>>3)][col][k&7]. Main kernel only
// stages/consumes Wh (W-lo product dropped; error budget analysis R9). ------
__global__ __launch_bounds__(256) void prep1(
    const float* __restrict__ W0, const float* __restrict__ Wn,
    const float* __restrict__ bn, const float* __restrict__ wcat,
    unsigned short* __restrict__ Wh, unsigned short* __restrict__ Wl,
    float* __restrict__ sortedTheta, int* __restrict__ rankArr)
{
    int tid = threadIdx.x;
    int gtid = blockIdx.x * 256 + tid;
    for (int idx = gtid; idx < OUTC * INC; idx += 8 * 256) {
        int col = idx >> 8;     // W0 is [112][256] row-major
        int k   = idx & 255;
        float w = W0[idx] * wcat[col * 2 + 0];
        unsigned short hi = bf16_rne(w);
        float resid = w - bf16_to_f32(hi);
        unsigned short lo = bf16_rne(resid);
        int dst = (k >> 3) * (OUTC * 8) + col * 8 + (k & 7);
        Wh[dst] = hi;
        Wl[dst] = lo;   // written but unused by main (kept for layout stability)
    }
    if (blockIdx.x == 0) {
        __shared__ float sth[128];
        float th = INFINITY;
        if (tid < 112) {
            float w = Wn[tid];
            th = (w != 0.0f) ? (-bn[tid] / w) : INFINITY;
        }
        if (tid < 128) sth[tid] = th;
        __syncthreads();
        if (tid < 128) {
            int rank = 0;
            for (int i = 0; i < 128; ++i) {
                float o = sth[i];
                rank += (o < th) || (o == th && i < tid);
            }
            sortedTheta[rank] = th;   // 128 entries; pads sort to top as +inf
            rankArr[tid] = rank;
        }
    }
}

// ---------------- Prepass 2: per-segment linear tables ----------------
__global__ __launch_bounds__(128) void prep2(
    const float* __restrict__ Wn, const float* __restrict__ bn,
    const float* __restrict__ Wc, const float* __restrict__ bc,
    const float* __restrict__ wcat, const float* __restrict__ bcat,
    const float* __restrict__ b0, const int* __restrict__ rankArr,
    float* __restrict__ Atab, float* __restrict__ Ctab)
{
    int s = blockIdx.x;      // 0..112
    int k = threadIdx.x;     // 0..127
    __shared__ float sw[112], sb[112];
    __shared__ int sr[112];
    if (k < 112) { sw[k] = Wn[k]; sb[k] = bn[k]; sr[k] = rankArr[k]; }
    __syncthreads();
    if (k >= OUTC) return;
    float a = 0.f, c = 0.f;
    const float* wcrow = Wc + k * OUTC;
    for (int j = 0; j < OUTC; ++j) {
        float w = sw[j];
        bool act = (w == 0.0f) ? (sb[j] > 0.0f)
                               : ((w > 0.0f) ? (sr[j] < s) : (sr[j] >= s));
        if (act) { float wc = wcrow[j]; a += wc * w; c += wc * sb[j]; }
    }
    float w1 = wcat[k * 2 + 1];
    Atab[s * OUTC + k] = w1 * a;
    Ctab[s * OUTC + k] = w1 * (c + bc[k]) + bcat[k] + wcat[k * 2 + 0] * b0[k];
}

// ---------------- Main kernel ----------------
// 512 threads = 8 waves x 32 rows (2 row-tiles) = 256 rows/block, 2 blocks/CU.
// W-hi only (57344 B) staged to LDS once, one __syncthreads, then a fully
// unrolled 8-kt loop: each kt = {conv x-hi/lo, prefetch kt+2, 7x(1 ds_read
// b128 shared by 4 MFMAs)}. x is the only vmcnt traffic; 2-kt prefetch
// distance (~2.2k cy) covers HBM latency. B-reads amortized over 32 rows.
__global__ __launch_bounds__(512, 4) void NodePredictor_main(
    const float* __restrict__ x, const float* __restrict__ node_info,
    const f32x4* __restrict__ Wg,          // Wh fragments, 3584 x 16B
    const float* __restrict__ sTheta,
    const float* __restrict__ Atab, const float* __restrict__ Ctab,
    float* __restrict__ out)
{
    __shared__ __align__(16) short LW[28672];   // 57344 B: Wh only
    __shared__ float sTh[128];

    const int tid  = threadIdx.x;
    const int lane = tid & 63;
    const int wv   = tid >> 6;           // 0..7
    const int l15  = lane & 15;
    const int kg   = lane >> 4;          // 0..3 k-group

    // ---- stage Wh into LDS: 3584 x 16B chunks = 512 threads x 7 ----
    {
        f32x4* dst = (f32x4*)LW;
        #pragma unroll
        for (int r = 0; r < 7; ++r) {
            int i = r * 512 + tid;
            dst[i] = Wg[i];
        }
    }
    if (tid < 128) sTh[tid] = sTheta[tid];
    __syncthreads();

    const long base = (long)blockIdx.x * 256 + wv * 32;
    const long row0 = base + l15;
    const long row1 = base + 16 + l15;
    const long row0c = row0 < NROWS ? row0 : (NROWS - 1);
    const long row1c = row1 < NROWS ? row1 : (NROWS - 1);
    const float* xr0 = x + row0c * (long)INC;
    const float* xr1 = x + row1c * (long)INC;

    f32x4 acc0[7], acc1[7];
    #pragma unroll
    for (int ct = 0; ct < 7; ++ct) {
        acc0[ct] = (f32x4){0.f, 0.f, 0.f, 0.f};
        acc1[ct] = (f32x4){0.f, 0.f, 0.f, 0.f};
    }

    // x buffers: A and B, 2 f32x4 per row-tile each (1 kt = 8 floats/lane)
    f32x4 a00, a01, a10, a11, b00, b01, b10, b11;
    #define LX(v00, v01, v10, v11, q) { \
        const float* p0_ = xr0 + (q) * 32 + kg * 8; \
        const float* p1_ = xr1 + (q) * 32 + kg * 8; \
        v00 = *(const f32x4*)p0_;  v01 = *(const f32x4*)(p0_ + 4); \
        v10 = *(const f32x4*)p1_;  v11 = *(const f32x4*)(p1_ + 4); }

    short8 h0, l0, h1, l1;
    #define MF(kt) { \
        _Pragma("unroll") \
        for (int ct = 0; ct < 7; ++ct) { \
            const short* bp_ = LW + ((kt) * 4 + kg) * 896 + (ct * 16 + l15) * 8; \
            short8 bh_ = *(const short8*)bp_; \
            acc0[ct] = __builtin_amdgcn_mfma_f32_16x16x32_bf16(bh_, h0, acc0[ct], 0, 0, 0); \
            acc0[ct] = __builtin_amdgcn_mfma_f32_16x16x32_bf16(bh_, l0, acc0[ct], 0, 0, 0); \
            acc1[ct] = __builtin_amdgcn_mfma_f32_16x16x32_bf16(bh_, h1, acc1[ct], 0, 0, 0); \
            acc1[ct] = __builtin_amdgcn_mfma_f32_16x16x32_bf16(bh_, l1, acc1[ct], 0, 0, 0); \
        } }

    LX(a00, a01, a10, a11, 0);
    LX(b00, b01, b10, b11, 1);

    // kt 0
    conv8(a00, a01, h0, l0); conv8(a10, a11, h1, l1);
    LX(a00, a01, a10, a11, 2);
    MF(0)
    // kt 1
    conv8(b00, b01, h0, l0); conv8(b10, b11, h1, l1);
    LX(b00, b01, b10, b11, 3);
    MF(1)
    // kt 2
    conv8(a00, a01, h0, l0); conv8(a10, a11, h1, l1);
    LX(a00, a01, a10, a11, 4);
    MF(2)
    // kt 3
    conv8(b00, b01, h0, l0); conv8(b10, b11, h1, l1);
    LX(b00, b01, b10, b11, 5);
    MF(3)
    // kt 4
    conv8(a00, a01, h0, l0); conv8(a10, a11, h1, l1);
    LX(a00, a01, a10, a11, 6);
    MF(4)
    // kt 5
    conv8(b00, b01, h0, l0); conv8(b10, b11, h1, l1);
    LX(b00, b01, b10, b11, 7);
    MF(5)
    // kt 6
    conv8(a00, a01, h0, l0); conv8(a10, a11, h1, l1);
    MF(6)
    // kt 7
    conv8(b00, b01, h0, l0); conv8(b10, b11, h1, l1);
    MF(7)

    // ---- epilogue: out[row][col..col+3] = acc + A[seg]*t + C[seg] ----
    float t0 = node_info[row0c];
    float t1 = node_info[row1c];
    int s0 = 0, s1 = 0;
    #pragma unroll
    for (int st = 64; st > 0; st >>= 1) {
        if (sTh[s0 + st - 1] < t0) s0 += st;   // #{theta < t}; pads are +inf
        if (sTh[s1 + st - 1] < t1) s1 += st;
    }

    if (row0 < NROWS) {
        const float* Ar = Atab + s0 * OUTC;
        const float* Cr = Ctab + s0 * OUTC;
        float* orow = out + row0 * (long)OUTC;
        #pragma unroll
        for (int ct = 0; ct < 7; ++ct) {
            int col = ct * 16 + kg * 4;
            f32x4 Av = *(const f32x4*)(Ar + col);
            f32x4 Cv = *(const f32x4*)(Cr + col);
            f32x4 v = acc0[ct], o;
            #pragma unroll
            for (int i = 0; i < 4; ++i) o[i] = v[i] + Av[i] * t0 + Cv[i];
            __builtin_nontemporal_store(o, (f32x4*)(orow + col));
        }
    }
    if (row1 < NROWS) {
        const float* Ar = Atab + s1 * OUTC;
        const float* Cr = Ctab + s1 * OUTC;
        float* orow = out + row1 * (long)OUTC;
        #pragma unroll
        for (int ct = 0; ct < 7; ++ct) {
            int col = ct * 16 + kg * 4;
            f32x4 Av = *(const f32x4*)(Ar + col);
            f32x4 Cv = *(const f32x4*)(Cr + col);
            f32x4 v = acc1[ct], o;
            #pragma unroll
            for (int i = 0; i < 4; ++i) o[i] = v[i] + Av[i] * t1 + Cv[i];
            __builtin_nontemporal_store(o, (f32x4*)(orow + col));
        }
    }
    #undef LX
    #undef MF
}

extern "C" void kernel_launch(void* const* d_in, const int* in_sizes, int n_in,
                              void* d_out, int out_size, void* d_ws, size_t ws_size,
                              hipStream_t stream)
{
    const float* x    = (const float*)d_in[0];
    const float* ni   = (const float*)d_in[1];
    const float* W0   = (const float*)d_in[2];
    const float* b0   = (const float*)d_in[3];
    const float* Wn   = (const float*)d_in[4];
    const float* bn   = (const float*)d_in[5];
    const float* Wc   = (const float*)d_in[6];
    const float* bc   = (const float*)d_in[7];
    const float* wcat = (const float*)d_in[8];
    const float* bcat = (const float*)d_in[9];
    float* out = (float*)d_out;

    char* ws = (char*)d_ws;
    unsigned short* Wh   = (unsigned short*)(ws);              // 57344 B
    unsigned short* Wl   = (unsigned short*)(ws + 57344);      // 57344 B (unused by main)
    float* sTheta        = (float*)(ws + 114688);              // 512 B
    int* rankArr         = (int*)(ws + 115200);                // 512 B
    float* Atab          = (float*)(ws + 115712);              // 50624 B
    float* Ctab          = (float*)(ws + 166336);              // 50624 B

    prep1<<<8, 256, 0, stream>>>(W0, Wn, bn, wcat, Wh, Wl, sTheta, rankArr);
    prep2<<<113, 128, 0, stream>>>(Wn, bn, Wc, bc, wcat, bcat, b0, rankArr, Atab, Ctab);

    const int blocks = (NROWS + 255) / 256;    // 1954
    NodePredictor_main<<<blocks, 512, 0, stream>>>(
        x, ni, (const f32x4*)ws, sTheta, Atab, Ctab, out);
}